// Round 4
// baseline (29391.885 us; speedup 1.0000x reference)
//
#include <hip/hip_runtime.h>
#include <hip/hip_bf16.h>

#define Vv 32000
#define Ee 256
#define Hh 256
#define Bb 32
#define TEe 128
#define TDd 64

typedef __attribute__((ext_vector_type(4))) float f32x4;
typedef __attribute__((ext_vector_type(8))) short short8;
typedef __attribute__((ext_vector_type(2))) unsigned int uint2v;
typedef __attribute__((ext_vector_type(4))) unsigned int uint4v;

static __device__ __forceinline__ unsigned short f2bf(float f){
  unsigned u = __float_as_uint(f);
  u += 0x7fffu + ((u >> 16) & 1u);           // round-to-nearest-even
  return (unsigned short)(u >> 16);
}
static __device__ __forceinline__ unsigned pack2(float a, float b){
  return ((unsigned)f2bf(b) << 16) | (unsigned)f2bf(a);
}
// dot of 8 packed bf16 (uint4) with 8 f32
static __device__ __forceinline__ float dot8(uint4v u, const float* hh){
  float s = 0.f;
  #pragma unroll
  for (int i = 0; i < 4; ++i){
    unsigned w = u[i];
    s = fmaf(__uint_as_float(w << 16),        hh[2*i],   s);
    s = fmaf(__uint_as_float(w & 0xffff0000u), hh[2*i+1], s);
  }
  return s;
}
static __device__ __forceinline__ float sigmoidf_(float x){
  return 1.f / (1.f + __expf(-x));
}

// ---------------- small prep kernels ----------------
__global__ void k_sizes(const int* __restrict__ enc_in, int* __restrict__ sizes){
  int b = threadIdx.x;
  if (b < Bb){
    int c = 0;
    for (int t = 0; t < TEe; ++t) c += (enc_in[b*TEe + t] > 0);
    sizes[b] = c;
  }
}

__global__ void k_gather(const int* __restrict__ tok, const float* __restrict__ embW,
                         float* __restrict__ out, int rows){
  int i = blockIdx.x * 256 + threadIdx.x;
  int r = i >> 8, c = i & 255;
  if (r < rows) out[i] = embW[(size_t)tok[r]*Ee + c];
}

// f32 -> bf16 row-major
__global__ void k_extract_bf16(const float* __restrict__ src, unsigned short* __restrict__ dst,
                               int n){
  int i = blockIdx.x * 256 + threadIdx.x;
  if (i < n) dst[i] = f2bf(src[i]);
}

// f32 [rows][256] -> chunked bf16 [32][rows][8]  (kb-major for coalesced staging)
__global__ void k_chunkw(const float* __restrict__ src, unsigned short* __restrict__ dst, int rows){
  int idx = blockIdx.x * 256 + threadIdx.x;
  if (idx < rows * 256){
    int i = idx & 7, r = (idx >> 3) % rows, kb = idx / (rows * 8);
    dst[idx] = f2bf(src[(size_t)r*256 + kb*8 + i]);
  }
}

// projf f32 [B*TE][768] -> chunked bf16 [B][16][768][8]
__global__ void k_projchunk(const float* __restrict__ in, unsigned short* __restrict__ out){
  int idx = blockIdx.x * 256 + threadIdx.x;     // total B*16*768*8
  int i = idx & 7;
  int t1 = idx >> 3;
  int n = t1 % 768;
  int t2 = t1 / 768;
  int kb = t2 & 15, b = t2 >> 4;
  out[idx] = f2bf(in[(size_t)(b*TEe + kb*8 + i)*768 + n]);
}

// ---------------- bf16 MFMA GEMM: C[M,N] = A[M,K] * B^T + bias ----------------
template<bool A_BF16, bool B_BF16, bool B_KMAJOR, bool OUT_BF16>
__global__ __launch_bounds__(256) void k_gemm(
  const void* __restrict__ Av, const void* __restrict__ Bv,
  const float* __restrict__ bias, void* __restrict__ Cv,
  int M, int N, int K, int lda, int ldb, int ldc)
{
  __shared__ unsigned short lA[128*40];
  __shared__ unsigned short lB[128*40];
  const int tid  = threadIdx.x;
  const int lane = tid & 63;
  const int w = tid >> 6, wr = w >> 1, wc = w & 1;
  const int m0 = blockIdx.y * 128, n0 = blockIdx.x * 128;
  f32x4 acc[4][4];
  #pragma unroll
  for (int i = 0; i < 4; ++i)
    #pragma unroll
    for (int j = 0; j < 4; ++j) acc[i][j] = (f32x4){0.f,0.f,0.f,0.f};

  for (int k0 = 0; k0 < K; k0 += 32){
    if (A_BF16){
      const unsigned short* A = (const unsigned short*)Av;
      #pragma unroll
      for (int it = 0; it < 2; ++it){
        int idx = tid + it*256; int r = idx >> 2, q = idx & 3;
        *(uint4v*)&lA[r*40 + q*8] = *(const uint4v*)(A + (size_t)(m0+r)*lda + k0 + q*8);
      }
    } else {
      const float* A = (const float*)Av;
      #pragma unroll
      for (int it = 0; it < 4; ++it){
        int idx = tid + it*256; int r = idx >> 3, q = idx & 7;
        f32x4 v = *(const f32x4*)(A + (size_t)(m0+r)*lda + k0 + q*4);
        uint2v pk; pk[0] = pack2(v[0], v[1]); pk[1] = pack2(v[2], v[3]);
        *(uint2v*)&lA[r*40 + q*4] = pk;
      }
    }
    if (B_KMAJOR){
      const float* Bp = (const float*)Bv;
      #pragma unroll
      for (int it = 0; it < 4; ++it){
        int idx = tid + it*256; int kk = idx >> 5, nq = idx & 31;
        f32x4 v = *(const f32x4*)(Bp + (size_t)(k0+kk)*ldb + n0 + nq*4);
        #pragma unroll
        for (int s2 = 0; s2 < 4; ++s2) lB[(nq*4+s2)*40 + kk] = f2bf(v[s2]);
      }
    } else if (B_BF16){
      const unsigned short* Bp = (const unsigned short*)Bv;
      #pragma unroll
      for (int it = 0; it < 2; ++it){
        int idx = tid + it*256; int r = idx >> 2, q = idx & 3;
        *(uint4v*)&lB[r*40 + q*8] = *(const uint4v*)(Bp + (size_t)(n0+r)*ldb + k0 + q*8);
      }
    } else {
      const float* Bp = (const float*)Bv;
      #pragma unroll
      for (int it = 0; it < 4; ++it){
        int idx = tid + it*256; int r = idx >> 3, q = idx & 7;
        f32x4 v = *(const f32x4*)(Bp + (size_t)(n0+r)*ldb + k0 + q*4);
        uint2v pk; pk[0] = pack2(v[0], v[1]); pk[1] = pack2(v[2], v[3]);
        *(uint2v*)&lB[r*40 + q*4] = pk;
      }
    }
    __syncthreads();
    short8 av[4], bv[4];
    #pragma unroll
    for (int i = 0; i < 4; ++i)
      av[i] = *(const short8*)&lA[(wr*64 + i*16 + (lane&15))*40 + (lane>>4)*8];
    #pragma unroll
    for (int j = 0; j < 4; ++j)
      bv[j] = *(const short8*)&lB[(wc*64 + j*16 + (lane&15))*40 + (lane>>4)*8];
    #pragma unroll
    for (int i = 0; i < 4; ++i)
      #pragma unroll
      for (int j = 0; j < 4; ++j)
        acc[i][j] = __builtin_amdgcn_mfma_f32_16x16x32_bf16(av[i], bv[j], acc[i][j], 0, 0, 0);
    __syncthreads();
  }
  #pragma unroll
  for (int i = 0; i < 4; ++i){
    #pragma unroll
    for (int j = 0; j < 4; ++j){
      int col = n0 + wc*64 + j*16 + (lane & 15);
      float bb = bias ? bias[col] : 0.f;
      #pragma unroll
      for (int r = 0; r < 4; ++r){
        int row = m0 + wr*64 + i*16 + (lane>>4)*4 + r;
        float v = acc[i][j][r] + bb;
        if (OUT_BF16) ((unsigned short*)Cv)[(size_t)row*ldc + col] = f2bf(v);
        else          ((float*)Cv)[(size_t)row*ldc + col] = v;
      }
    }
  }
}

// ---------------- encoder recurrence: 64 blocks = (dir, batch), 256 threads ----------------
// Thread j holds Wh rows {j, j+256, j+512} as packed bf16 in 96 uint4v registers.
// One barrier per step via double-buffered h. Zero steady-state global weight traffic.
__global__ __launch_bounds__(256) void k_encoder(
  const unsigned short* __restrict__ Whf, const unsigned short* __restrict__ Whb,
  const float* __restrict__ bhf, const float* __restrict__ bhb,
  const float* __restrict__ gif, const float* __restrict__ gib,
  float* __restrict__ encoded)
{
  __shared__ float hA[Hh], hB[Hh];
  const int dir = blockIdx.x & 1, b = blockIdx.x >> 1;
  const unsigned short* Wh = dir ? Whb : Whf;
  const float* bh = dir ? bhb : bhf;
  const float* gi = dir ? gib : gif;
  const int j = threadIdx.x;
  uint4v w0[32], w1[32], w2[32];
  #pragma unroll
  for (int q = 0; q < 32; ++q){
    w0[q] = *(const uint4v*)(Wh + (size_t)q*6144 + j*8);
    w1[q] = *(const uint4v*)(Wh + (size_t)q*6144 + (j+256)*8);
    w2[q] = *(const uint4v*)(Wh + (size_t)q*6144 + (j+512)*8);
  }
  const float bh0 = bh[j], bh1 = bh[j+256], bh2 = bh[j+512];
  hA[j] = 0.f;
  __syncthreads();
  const float* hc = hA; float* hn = hB;
  for (int s = 0; s < TEe; ++s){
    const int t = dir ? (TEe-1-s) : s;
    const float* grow = gi + (size_t)(b*TEe + t)*768;
    const float g0 = grow[j], g1 = grow[j+256], g2 = grow[j+512];
    float a0 = bh0, a1 = bh1, a2 = bh2;
    #pragma unroll
    for (int q = 0; q < 32; ++q){
      float hr[8];
      *(f32x4*)&hr[0] = *(const f32x4*)&hc[q*8];
      *(f32x4*)&hr[4] = *(const f32x4*)&hc[q*8+4];
      a0 += dot8(w0[q], hr);
      a1 += dot8(w1[q], hr);
      a2 += dot8(w2[q], hr);
    }
    const float r = sigmoidf_(g0 + a0);
    const float z = sigmoidf_(g1 + a1);
    const float n = tanhf(g2 + r*a2);
    const float hnew = (1.f - z)*n + z*hc[j];
    hn[j] = hnew;
    encoded[(size_t)(b*TEe + t)*512 + dir*256 + j] = hnew;
    __syncthreads();   // hn visible; old hc fully read -> safe to overwrite next step
    const float* tmp = hc; hc = hn; hn = (float*)tmp;
  }
}

// encb2[r] = encoded[r,:512] . W2_b
__global__ void k_encb2(const float* __restrict__ encoded, const float* __restrict__ W2b,
                        float* __restrict__ encb2){
  int r = blockIdx.x, l = threadIdx.x;
  const float* e = encoded + (size_t)r*512;
  float s = 0.f;
  for (int k = l; k < 512; k += 64) s += e[k]*W2b[k];
  for (int off = 32; off; off >>= 1) s += __shfl_down(s, off);
  if (l == 0) encb2[r] = s;
}

__global__ void k_hinit(const float* __restrict__ encoded, const int* __restrict__ sizes,
                        const float* __restrict__ W1w, const float* __restrict__ W1b,
                        float* __restrict__ h0){
  int b = blockIdx.x, o = threadIdx.x;
  int idx = sizes[b] - 1;
  idx = idx < 0 ? 0 : (idx > TEe-1 ? TEe-1 : idx);
  const float* ls = encoded + (size_t)(b*TEe + idx)*512;
  const float* wv = W1w + (size_t)o*512;
  float s = W1b[o];
  for (int k = 0; k < 512; k += 4){
    f32x4 a = *(const f32x4*)(ls + k);
    f32x4 w4 = *(const f32x4*)(wv + k);
    s = fmaf(a[0],w4[0], fmaf(a[1],w4[1], fmaf(a[2],w4[2], fmaf(a[3],w4[3], s))));
  }
  h0[b*256 + o] = s;
}

// ---------------- decoder: 32 blocks = batch, 768 threads, 3 specialized groups ----------------
// G1 (tid 0-255):   Whd rows {j,j+256,j+512} in regs -> GRU cell
// G2 (tid 256-511): projt rows {n,n+256,n+512} in regs -> ctx projection (gcs)
// G3 (tid 512-767): encw2 half-rows in regs -> attention scores (+ wave softmax)
// All groups share one rg[96] register array (union) to avoid >512 VGPR demand.
// n-gate: ctx projection stays OUTSIDE the r* product (ref semantics).
__global__ __launch_bounds__(768) void k_decoder(
  const unsigned short* __restrict__ Whd, const float* __restrict__ bhd,
  const float* __restrict__ gidx,            // [B][TD][768] f32 (includes bi_d)
  const unsigned short* __restrict__ encw2,  // [B*TE][256] bf16
  const float* __restrict__ encb2,           // [B*TE]
  const unsigned short* __restrict__ projt,  // [B][16][768][8] bf16
  const float* __restrict__ h0,
  unsigned short* __restrict__ outs_bf)      // [B][TD][256] bf16
{
  __shared__ float hA[Hh], hB[Hh], p[TEe], gcs[768];
  const int b = blockIdx.x, tid = threadIdx.x;
  const int i2 = tid & 255;
  const unsigned short* ptc = projt + (size_t)b*98304;
  uint4v rg[96];
  float bh0 = 0.f, bh1 = 0.f, bh2 = 0.f, eb = 0.f;
  if (tid < 256){
    #pragma unroll
    for (int q = 0; q < 32; ++q){
      rg[q]    = *(const uint4v*)(Whd + (size_t)q*6144 + i2*8);
      rg[32+q] = *(const uint4v*)(Whd + (size_t)q*6144 + (i2+256)*8);
      rg[64+q] = *(const uint4v*)(Whd + (size_t)q*6144 + (i2+512)*8);
    }
    bh0 = bhd[i2]; bh1 = bhd[i2+256]; bh2 = bhd[i2+512];
    hA[i2] = h0[b*256 + i2];
  } else if (tid < 512){
    #pragma unroll
    for (int q = 0; q < 16; ++q){
      rg[q]    = *(const uint4v*)(ptc + (size_t)q*6144 + i2*8);
      rg[16+q] = *(const uint4v*)(ptc + (size_t)q*6144 + (i2+256)*8);
      rg[32+q] = *(const uint4v*)(ptc + (size_t)q*6144 + (i2+512)*8);
    }
  } else {
    const int tt = i2 >> 1, kh = i2 & 1;
    #pragma unroll
    for (int q = 0; q < 16; ++q)
      rg[q] = *(const uint4v*)(encw2 + (((size_t)(b*TEe + tt)) << 8) + kh*128 + q*8);
    eb = encb2[b*TEe + tt];
  }
  gcs[tid] = 0.f;                     // ctx_init = 0
  __syncthreads();
  const float* hc = hA; float* hn = hB;
  for (int t = 0; t < TDd; ++t){
    if (tid < 256){
      const float* grow = gidx + (size_t)(b*TDd + t)*768;
      const float g0 = grow[i2], g1 = grow[i2+256], g2 = grow[i2+512];
      float a0 = bh0, a1 = bh1, a2 = bh2;
      #pragma unroll
      for (int q = 0; q < 32; ++q){
        float hr[8];
        *(f32x4*)&hr[0] = *(const f32x4*)&hc[q*8];
        *(f32x4*)&hr[4] = *(const f32x4*)&hc[q*8+4];
        a0 += dot8(rg[q], hr);
        a1 += dot8(rg[32+q], hr);
        a2 += dot8(rg[64+q], hr);
      }
      const float r = sigmoidf_(g0 + gcs[i2] + a0);
      const float z = sigmoidf_(g1 + gcs[i2+256] + a1);
      const float n = tanhf(g2 + gcs[i2+512] + r*a2);
      const float hnew = (1.f - z)*n + z*hc[i2];
      hn[i2] = hnew;
      outs_bf[(size_t)(b*TDd + t)*256 + i2] = f2bf(hnew);
    }
    __syncthreads();                  // B1: h_new visible
    if (tid >= 512){
      const int tt = i2 >> 1, kh = i2 & 1;
      float s = 0.f;
      #pragma unroll
      for (int q = 0; q < 16; ++q){
        float hr[8];
        *(f32x4*)&hr[0] = *(const f32x4*)&hn[kh*128 + q*8];
        *(f32x4*)&hr[4] = *(const f32x4*)&hn[kh*128 + q*8 + 4];
        s += dot8(rg[q], hr);
      }
      s += __shfl_xor(s, 1);
      if (kh == 0) p[tt] = s + eb;
    }
    __syncthreads();                  // B2: raw scores visible
    if (tid >= 512 && tid < 576){
      const int l = tid - 512;
      float m = fmaxf(p[l], p[l+64]);
      for (int off = 32; off; off >>= 1) m = fmaxf(m, __shfl_xor(m, off));
      float e0 = __expf(p[l] - m), e1 = __expf(p[l+64] - m);
      float ss = e0 + e1;
      for (int off = 32; off; off >>= 1) ss += __shfl_xor(ss, off);
      float inv = 1.f / ss;
      p[l] = e0*inv; p[l+64] = e1*inv;
    }
    __syncthreads();                  // B3: softmax done
    if (tid >= 256 && tid < 512){
      float c0 = 0.f, c1 = 0.f, c2 = 0.f;
      #pragma unroll
      for (int q = 0; q < 16; ++q){
        float pr[8];
        *(f32x4*)&pr[0] = *(const f32x4*)&p[q*8];
        *(f32x4*)&pr[4] = *(const f32x4*)&p[q*8+4];
        c0 += dot8(rg[q], pr);
        c1 += dot8(rg[16+q], pr);
        c2 += dot8(rg[32+q], pr);
      }
      gcs[i2] = c0; gcs[i2+256] = c1; gcs[i2+512] = c2;
    }
    __syncthreads();                  // B4: gcs for next step
    const float* tmp = hc; hc = hn; hn = (float*)tmp;
  }
}

extern "C" void kernel_launch(void* const* d_in, const int* in_sizes, int n_in,
                              void* d_out, int out_size, void* d_ws, size_t ws_size,
                              hipStream_t stream)
{
  (void)in_sizes; (void)n_in; (void)out_size;
  const int*   enc_in = (const int*)d_in[0];
  const int*   dec_in = (const int*)d_in[1];
  const float* embW   = (const float*)d_in[2];
  const float* Wi_f   = (const float*)d_in[3];
  const float* Wh_f   = (const float*)d_in[4];
  const float* bi_f   = (const float*)d_in[5];
  const float* bh_f   = (const float*)d_in[6];
  const float* Wi_b   = (const float*)d_in[7];
  const float* Wh_b   = (const float*)d_in[8];
  const float* bi_b   = (const float*)d_in[9];
  const float* bh_b   = (const float*)d_in[10];
  const float* Wi_d   = (const float*)d_in[11];
  const float* Wh_d   = (const float*)d_in[12];
  const float* bi_d   = (const float*)d_in[13];
  const float* bh_d   = (const float*)d_in[14];
  const float* W1_w   = (const float*)d_in[15];
  const float* W1_b   = (const float*)d_in[16];
  const float* W2_w   = (const float*)d_in[17];
  const float* W2_b   = (const float*)d_in[18];
  const float* lin_w  = (const float*)d_in[19];
  const float* lin_b  = (const float*)d_in[20];

  char* scr = (char*)d_out;
  float* emb_enc = (float*)(scr + 0);
  float* emb_dec = (float*)(scr + 4194304);
  float* gi_f    = (float*)(scr + 6291456);
  float* gi_b    = (float*)(scr + 18874368);
  float* gi_dx   = (float*)(scr + 31457280);
  float* enc     = (float*)(scr + 37748736);
  float* projf   = (float*)(scr + 46137344);
  unsigned short* whf_bf = (unsigned short*)(scr + 58720256);
  unsigned short* whb_bf = (unsigned short*)(scr + 59113472);
  unsigned short* whd_bf = (unsigned short*)(scr + 59506688);
  unsigned short* encw2  = (unsigned short*)(scr + 59899904);
  unsigned short* projt  = (unsigned short*)(scr + 61997056);
  float* encb2 = (float*)(scr + 68288512);
  int*   sizes = (int*)(scr + 68304896);
  float* h0    = (float*)(scr + 68305024);

  unsigned short* outs_bf = (unsigned short*)d_ws;
  unsigned short* lin_bf  = (unsigned short*)((char*)d_ws + (1<<20));
  const bool big = ws_size >= (size_t)(1<<20) + 16384000u + 1024u;

  k_sizes<<<1, 32, 0, stream>>>(enc_in, sizes);
  k_gather<<<Bb*TEe, 256, 0, stream>>>(enc_in, embW, emb_enc, Bb*TEe);
  k_gather<<<Bb*TDd, 256, 0, stream>>>(dec_in, embW, emb_dec, Bb*TDd);
  k_chunkw<<<768, 256, 0, stream>>>(Wh_f, whf_bf, 768);
  k_chunkw<<<768, 256, 0, stream>>>(Wh_b, whb_bf, 768);
  k_chunkw<<<768, 256, 0, stream>>>(Wh_d, whd_bf, 768);
  if (big) k_extract_bf16<<<32000, 256, 0, stream>>>(lin_w, lin_bf, 32000*256);

  k_gemm<false,false,false,false><<<dim3(6,32), 256, 0, stream>>>(
      emb_enc, Wi_f, bi_f, gi_f, 4096, 768, 256, 256, 256, 768);
  k_gemm<false,false,false,false><<<dim3(6,32), 256, 0, stream>>>(
      emb_enc, Wi_b, bi_b, gi_b, 4096, 768, 256, 256, 256, 768);
  k_gemm<false,false,false,false><<<dim3(6,16), 256, 0, stream>>>(
      emb_dec, Wi_d + 512, bi_d, gi_dx, 2048, 768, 256, 256, 768, 768);

  k_encoder<<<64, 256, 0, stream>>>(whf_bf, whb_bf, bh_f, bh_b, gi_f, gi_b, enc);
  k_encb2<<<Bb*TEe, 64, 0, stream>>>(enc, W2_b, encb2);

  k_gemm<false,false,true,true><<<dim3(2,32), 256, 0, stream>>>(
      enc, W2_w, nullptr, encw2, 4096, 256, 512, 512, 256, 256);
  k_gemm<false,false,false,false><<<dim3(6,32), 256, 0, stream>>>(
      enc, Wi_d, nullptr, projf, 4096, 768, 512, 512, 768, 768);
  k_projchunk<<<(Bb*16*768*8)/256, 256, 0, stream>>>(projf, projt);
  k_hinit<<<Bb, 256, 0, stream>>>(enc, sizes, W1_w, W1_b, h0);

  k_decoder<<<Bb, 768, 0, stream>>>(whd_bf, bh_d, gi_dx, encw2, encb2, projt, h0, outs_bf);

  if (big)
    k_gemm<true,true,false,false><<<dim3(250,16), 256, 0, stream>>>(
        outs_bf, lin_bf, lin_b, d_out, 2048, 32000, 256, 256, 256, 32000);
  else
    k_gemm<true,false,false,false><<<dim3(250,16), 256, 0, stream>>>(
        outs_bf, lin_w, lin_b, d_out, 2048, 32000, 256, 256, 256, 32000);
}

// Round 5
// 5057.656 us; speedup vs baseline: 5.8114x; 5.8114x over previous
//
#include <hip/hip_runtime.h>
#include <hip/hip_bf16.h>

#define Vv 32000
#define Ee 256
#define Hh 256
#define Bb 32
#define TEe 128
#define TDd 64

typedef __attribute__((ext_vector_type(4))) float f32x4;
typedef __attribute__((ext_vector_type(8))) short short8;
typedef __attribute__((ext_vector_type(2))) unsigned int uint2v;
typedef __attribute__((ext_vector_type(4))) unsigned int uint4v;

static __device__ __forceinline__ unsigned short f2bf(float f){
  unsigned u = __float_as_uint(f);
  u += 0x7fffu + ((u >> 16) & 1u);           // round-to-nearest-even
  return (unsigned short)(u >> 16);
}
static __device__ __forceinline__ unsigned pack2(float a, float b){
  return ((unsigned)f2bf(b) << 16) | (unsigned)f2bf(a);
}
// dot of 8 packed bf16 (uint4) with 8 f32
static __device__ __forceinline__ float dot8(uint4v u, const float* hh){
  float s = 0.f;
  #pragma unroll
  for (int i = 0; i < 4; ++i){
    unsigned w = u[i];
    s = fmaf(__uint_as_float(w << 16),        hh[2*i],   s);
    s = fmaf(__uint_as_float(w & 0xffff0000u), hh[2*i+1], s);
  }
  return s;
}
static __device__ __forceinline__ float sigmoidf_(float x){
  return 1.f / (1.f + __expf(-x));
}

// ---------------- small prep kernels ----------------
__global__ void k_sizes(const int* __restrict__ enc_in, int* __restrict__ sizes){
  int b = threadIdx.x;
  if (b < Bb){
    int c = 0;
    for (int t = 0; t < TEe; ++t) c += (enc_in[b*TEe + t] > 0);
    sizes[b] = c;
  }
}

__global__ void k_gather(const int* __restrict__ tok, const float* __restrict__ embW,
                         float* __restrict__ out, int rows){
  int i = blockIdx.x * 256 + threadIdx.x;
  int r = i >> 8, c = i & 255;
  if (r < rows) out[i] = embW[(size_t)tok[r]*Ee + c];
}

// f32 -> bf16 row-major
__global__ void k_extract_bf16(const float* __restrict__ src, unsigned short* __restrict__ dst,
                               int n){
  int i = blockIdx.x * 256 + threadIdx.x;
  if (i < n) dst[i] = f2bf(src[i]);
}

// f32 [rows][256] -> chunked bf16 [32][rows][8]  (kb-major for coalesced staging)
__global__ void k_chunkw(const float* __restrict__ src, unsigned short* __restrict__ dst, int rows){
  int idx = blockIdx.x * 256 + threadIdx.x;
  if (idx < rows * 256){
    int i = idx & 7, r = (idx >> 3) % rows, kb = idx / (rows * 8);
    dst[idx] = f2bf(src[(size_t)r*256 + kb*8 + i]);
  }
}

// projf f32 [B*TE][768] -> chunked bf16 [B][16][768][8]
__global__ void k_projchunk(const float* __restrict__ in, unsigned short* __restrict__ out){
  int idx = blockIdx.x * 256 + threadIdx.x;     // total B*16*768*8
  int i = idx & 7;
  int t1 = idx >> 3;
  int n = t1 % 768;
  int t2 = t1 / 768;
  int kb = t2 & 15, b = t2 >> 4;
  out[idx] = f2bf(in[(size_t)(b*TEe + kb*8 + i)*768 + n]);
}

// ---------------- bf16 MFMA GEMM: C[M,N] = A[M,K] * B^T + bias ----------------
template<bool A_BF16, bool B_BF16, bool B_KMAJOR, bool OUT_BF16>
__global__ __launch_bounds__(256) void k_gemm(
  const void* __restrict__ Av, const void* __restrict__ Bv,
  const float* __restrict__ bias, void* __restrict__ Cv,
  int M, int N, int K, int lda, int ldb, int ldc)
{
  __shared__ unsigned short lA[128*40];
  __shared__ unsigned short lB[128*40];
  const int tid  = threadIdx.x;
  const int lane = tid & 63;
  const int w = tid >> 6, wr = w >> 1, wc = w & 1;
  const int m0 = blockIdx.y * 128, n0 = blockIdx.x * 128;
  f32x4 acc[4][4];
  #pragma unroll
  for (int i = 0; i < 4; ++i)
    #pragma unroll
    for (int j = 0; j < 4; ++j) acc[i][j] = (f32x4){0.f,0.f,0.f,0.f};

  for (int k0 = 0; k0 < K; k0 += 32){
    if (A_BF16){
      const unsigned short* A = (const unsigned short*)Av;
      #pragma unroll
      for (int it = 0; it < 2; ++it){
        int idx = tid + it*256; int r = idx >> 2, q = idx & 3;
        *(uint4v*)&lA[r*40 + q*8] = *(const uint4v*)(A + (size_t)(m0+r)*lda + k0 + q*8);
      }
    } else {
      const float* A = (const float*)Av;
      #pragma unroll
      for (int it = 0; it < 4; ++it){
        int idx = tid + it*256; int r = idx >> 3, q = idx & 7;
        f32x4 v = *(const f32x4*)(A + (size_t)(m0+r)*lda + k0 + q*4);
        uint2v pk; pk[0] = pack2(v[0], v[1]); pk[1] = pack2(v[2], v[3]);
        *(uint2v*)&lA[r*40 + q*4] = pk;
      }
    }
    if (B_KMAJOR){
      const float* Bp = (const float*)Bv;
      #pragma unroll
      for (int it = 0; it < 4; ++it){
        int idx = tid + it*256; int kk = idx >> 5, nq = idx & 31;
        f32x4 v = *(const f32x4*)(Bp + (size_t)(k0+kk)*ldb + n0 + nq*4);
        #pragma unroll
        for (int s2 = 0; s2 < 4; ++s2) lB[(nq*4+s2)*40 + kk] = f2bf(v[s2]);
      }
    } else if (B_BF16){
      const unsigned short* Bp = (const unsigned short*)Bv;
      #pragma unroll
      for (int it = 0; it < 2; ++it){
        int idx = tid + it*256; int r = idx >> 2, q = idx & 3;
        *(uint4v*)&lB[r*40 + q*8] = *(const uint4v*)(Bp + (size_t)(n0+r)*ldb + k0 + q*8);
      }
    } else {
      const float* Bp = (const float*)Bv;
      #pragma unroll
      for (int it = 0; it < 4; ++it){
        int idx = tid + it*256; int r = idx >> 3, q = idx & 7;
        f32x4 v = *(const f32x4*)(Bp + (size_t)(n0+r)*ldb + k0 + q*4);
        uint2v pk; pk[0] = pack2(v[0], v[1]); pk[1] = pack2(v[2], v[3]);
        *(uint2v*)&lB[r*40 + q*4] = pk;
      }
    }
    __syncthreads();
    short8 av[4], bv[4];
    #pragma unroll
    for (int i = 0; i < 4; ++i)
      av[i] = *(const short8*)&lA[(wr*64 + i*16 + (lane&15))*40 + (lane>>4)*8];
    #pragma unroll
    for (int j = 0; j < 4; ++j)
      bv[j] = *(const short8*)&lB[(wc*64 + j*16 + (lane&15))*40 + (lane>>4)*8];
    #pragma unroll
    for (int i = 0; i < 4; ++i)
      #pragma unroll
      for (int j = 0; j < 4; ++j)
        acc[i][j] = __builtin_amdgcn_mfma_f32_16x16x32_bf16(av[i], bv[j], acc[i][j], 0, 0, 0);
    __syncthreads();
  }
  #pragma unroll
  for (int i = 0; i < 4; ++i){
    #pragma unroll
    for (int j = 0; j < 4; ++j){
      int col = n0 + wc*64 + j*16 + (lane & 15);
      float bb = bias ? bias[col] : 0.f;
      #pragma unroll
      for (int r = 0; r < 4; ++r){
        int row = m0 + wr*64 + i*16 + (lane>>4)*4 + r;
        float v = acc[i][j][r] + bb;
        if (OUT_BF16) ((unsigned short*)Cv)[(size_t)row*ldc + col] = f2bf(v);
        else          ((float*)Cv)[(size_t)row*ldc + col] = v;
      }
    }
  }
}

// ---------------- encoder recurrence: 64 blocks = (dir, batch), 512 threads ----------------
// Thread T owns half (T>>8) of Wh rows {r0, r0+256, r0+512} in 48 uint4v = 192 VGPRs
// (sized so 2 waves/SIMD fit the 512-VGPR/SIMD file; R4's 384-reg arrays spilled).
// Partial dots -> par[1536] in LDS; gate threads combine halves. 2 barriers/step.
__global__ __launch_bounds__(512, 2) void k_encoder(
  const unsigned short* __restrict__ Whf, const unsigned short* __restrict__ Whb,
  const float* __restrict__ bhf, const float* __restrict__ bhb,
  const float* __restrict__ gif, const float* __restrict__ gib,
  float* __restrict__ encoded)
{
  __shared__ float hA[Hh], hB[Hh], par[1536];
  const int dir = blockIdx.x & 1, b = blockIdx.x >> 1;
  const unsigned short* Wh = dir ? Whb : Whf;
  const float* bh = dir ? bhb : bhf;
  const float* gi = dir ? gib : gif;
  const int T = threadIdx.x;
  const int half = T >> 8, r0 = T & 255;
  uint4v w0[16], w1[16], w2[16];
  #pragma unroll
  for (int q = 0; q < 16; ++q){
    const unsigned short* base = Wh + (size_t)(half*16 + q)*6144;
    w0[q] = *(const uint4v*)(base + r0*8);
    w1[q] = *(const uint4v*)(base + (r0+256)*8);
    w2[q] = *(const uint4v*)(base + (r0+512)*8);
  }
  float bh0 = 0.f, bh1 = 0.f, bh2 = 0.f;
  if (T < 256){ bh0 = bh[T]; bh1 = bh[T+256]; bh2 = bh[T+512]; hA[T] = 0.f; }
  __syncthreads();
  const float* hc = hA; float* hn = hB;
  for (int s = 0; s < TEe; ++s){
    const int t = dir ? (TEe-1-s) : s;
    float a0 = 0.f, a1 = 0.f, a2 = 0.f;
    const float* hh = hc + half*128;
    #pragma unroll
    for (int q = 0; q < 16; ++q){
      float hr[8];
      *(f32x4*)&hr[0] = *(const f32x4*)&hh[q*8];
      *(f32x4*)&hr[4] = *(const f32x4*)&hh[q*8+4];
      a0 += dot8(w0[q], hr);
      a1 += dot8(w1[q], hr);
      a2 += dot8(w2[q], hr);
    }
    par[half*768 + r0]       = a0;
    par[half*768 + r0 + 256] = a1;
    par[half*768 + r0 + 512] = a2;
    __syncthreads();                   // B1: partials ready
    if (T < 256){
      const float* grow = gi + (size_t)(b*TEe + t)*768;
      const float A0 = par[T]     + par[768+T]     + bh0;
      const float A1 = par[T+256] + par[768+T+256] + bh1;
      const float A2 = par[T+512] + par[768+T+512] + bh2;
      const float r = sigmoidf_(grow[T] + A0);
      const float z = sigmoidf_(grow[T+256] + A1);
      const float n = tanhf(grow[T+512] + r*A2);
      const float hnew = (1.f - z)*n + z*hc[T];
      hn[T] = hnew;
      encoded[(size_t)(b*TEe + t)*512 + dir*256 + T] = hnew;
    }
    __syncthreads();                   // B2: h_new visible; old hc fully consumed
    const float* tmp = hc; hc = hn; hn = (float*)tmp;
  }
}

// encb2[r] = encoded[r,:512] . W2_b
__global__ void k_encb2(const float* __restrict__ encoded, const float* __restrict__ W2b,
                        float* __restrict__ encb2){
  int r = blockIdx.x, l = threadIdx.x;
  const float* e = encoded + (size_t)r*512;
  float s = 0.f;
  for (int k = l; k < 512; k += 64) s += e[k]*W2b[k];
  for (int off = 32; off; off >>= 1) s += __shfl_down(s, off);
  if (l == 0) encb2[r] = s;
}

__global__ void k_hinit(const float* __restrict__ encoded, const int* __restrict__ sizes,
                        const float* __restrict__ W1w, const float* __restrict__ W1b,
                        float* __restrict__ h0){
  int b = blockIdx.x, o = threadIdx.x;
  int idx = sizes[b] - 1;
  idx = idx < 0 ? 0 : (idx > TEe-1 ? TEe-1 : idx);
  const float* ls = encoded + (size_t)(b*TEe + idx)*512;
  const float* wv = W1w + (size_t)o*512;
  float s = W1b[o];
  for (int k = 0; k < 512; k += 4){
    f32x4 a = *(const f32x4*)(ls + k);
    f32x4 w4 = *(const f32x4*)(wv + k);
    s = fmaf(a[0],w4[0], fmaf(a[1],w4[1], fmaf(a[2],w4[2], fmaf(a[3],w4[3], s))));
  }
  h0[b*256 + o] = s;
}

// ---------------- decoder: 32 blocks = batch, 512 threads ----------------
// Whd half-rows in registers (192 VGPR/thread, uniform across all threads);
// encw2[b] in LDS (64 KB, XOR-swizzled); projt streamed from L2 in ctx phase.
// n-gate: ctx projection (gc) stays OUTSIDE the r* product (ref semantics).
__global__ __launch_bounds__(512, 2) void k_decoder(
  const unsigned short* __restrict__ Whd, const float* __restrict__ bhd,
  const float* __restrict__ gidx,            // [B][TD][768] f32 (includes bi_d)
  const unsigned short* __restrict__ encw2,  // [B*TE][256] bf16
  const float* __restrict__ encb2,           // [B*TE]
  const unsigned short* __restrict__ projt,  // [B][16][768][8] bf16
  const float* __restrict__ h0,
  unsigned short* __restrict__ outs_bf)      // [B][TD][256] bf16
{
  extern __shared__ char smem[];
  unsigned short* le = (unsigned short*)smem;      // 65536
  float* par  = (float*)(smem + 65536);            // 6144
  float* par2 = (float*)(smem + 71680);            // 6144
  float* hA   = (float*)(smem + 77824);            // 1024
  float* hB   = (float*)(smem + 78848);            // 1024
  float* p    = (float*)(smem + 79872);            // 512  -> total 80384
  const int b = blockIdx.x, T = threadIdx.x;
  const int half = T >> 8, r0 = T & 255;
  // stage encw2[b] (rows XOR-swizzled by k-chunk)
  for (int cc = T; cc < 128*32; cc += 512){
    int r = cc >> 5, q = cc & 31;
    *(uint4v*)&le[(r*32 + (q ^ (r & 31)))*8] =
        *(const uint4v*)(encw2 + ((size_t)(b*TEe + r) << 8) + (q << 3));
  }
  uint4v w0[16], w1[16], w2[16];
  #pragma unroll
  for (int q = 0; q < 16; ++q){
    const unsigned short* base = Whd + (size_t)(half*16 + q)*6144;
    w0[q] = *(const uint4v*)(base + r0*8);
    w1[q] = *(const uint4v*)(base + (r0+256)*8);
    w2[q] = *(const uint4v*)(base + (r0+512)*8);
  }
  const unsigned short* ptc = projt + (size_t)b*98304 + (size_t)half*8*6144;
  const float eb = encb2[b*TEe + (T >> 2)];
  float bh0 = 0.f, bh1 = 0.f, bh2 = 0.f;
  if (T < 256){
    bh0 = bhd[T]; bh1 = bhd[T+256]; bh2 = bhd[T+512];
    hA[T] = h0[b*256 + T];
  }
  par2[T] = 0.f; par2[T+512] = 0.f; par2[T+1024] = 0.f;   // ctx_init = 0
  __syncthreads();
  const float* hc = hA; float* hn = hB;
  for (int t = 0; t < TDd; ++t){
    // phase 1: GRU partial dots from register weights
    {
      float a0 = 0.f, a1 = 0.f, a2 = 0.f;
      const float* hh = hc + half*128;
      #pragma unroll
      for (int q = 0; q < 16; ++q){
        float hr[8];
        *(f32x4*)&hr[0] = *(const f32x4*)&hh[q*8];
        *(f32x4*)&hr[4] = *(const f32x4*)&hh[q*8+4];
        a0 += dot8(w0[q], hr);
        a1 += dot8(w1[q], hr);
        a2 += dot8(w2[q], hr);
      }
      par[half*768 + r0]       = a0;
      par[half*768 + r0 + 256] = a1;
      par[half*768 + r0 + 512] = a2;
    }
    __syncthreads();                   // B1
    if (T < 256){
      const float* grow = gidx + (size_t)(b*TDd + t)*768;
      const float A0 = par[T]     + par[768+T]     + bh0;
      const float A1 = par[T+256] + par[768+T+256] + bh1;
      const float A2 = par[T+512] + par[768+T+512] + bh2;
      const float gc0 = par2[T]     + par2[768+T];
      const float gc1 = par2[T+256] + par2[768+T+256];
      const float gc2 = par2[T+512] + par2[768+T+512];
      const float r = sigmoidf_(grow[T] + gc0 + A0);
      const float z = sigmoidf_(grow[T+256] + gc1 + A1);
      const float n = tanhf(grow[T+512] + gc2 + r*A2);
      const float hnew = (1.f - z)*n + z*hc[T];
      hn[T] = hnew;
      outs_bf[(size_t)(b*TDd + t)*256 + T] = f2bf(hnew);
    }
    __syncthreads();                   // B2: h_new visible
    // phase 3: scores from LDS encw2, 4-thread k-split per row
    {
      const int tt = T >> 2, l = T & 3, tx = tt & 31;
      const unsigned short* er = le + tt*256;
      const float* hh = hn + l*64;
      float s = 0.f;
      #pragma unroll
      for (int i = 0; i < 8; ++i){
        const int q = l*8 + i;
        float hr[8];
        *(f32x4*)&hr[0] = *(const f32x4*)&hh[i*8];
        *(f32x4*)&hr[4] = *(const f32x4*)&hh[i*8+4];
        s += dot8(*(const uint4v*)(er + ((q ^ tx) << 3)), hr);
      }
      s += __shfl_xor(s, 1);
      s += __shfl_xor(s, 2);
      if (l == 0) p[tt] = s + eb;
    }
    __syncthreads();                   // B3
    if (T < 64){
      float m = fmaxf(p[T], p[T+64]);
      for (int off = 32; off; off >>= 1) m = fmaxf(m, __shfl_xor(m, off));
      float e0 = __expf(p[T] - m), e1 = __expf(p[T+64] - m);
      float ss = e0 + e1;
      for (int off = 32; off; off >>= 1) ss += __shfl_xor(ss, off);
      float inv = 1.f / ss;
      p[T] = e0*inv; p[T+64] = e1*inv;
    }
    __syncthreads();                   // B4: softmax done
    // phase 5: ctx projection partials (projt streamed from L2)
    {
      float c0 = 0.f, c1 = 0.f, c2 = 0.f;
      const float* pp = p + half*64;
      #pragma unroll
      for (int q = 0; q < 8; ++q){
        float pr[8];
        *(f32x4*)&pr[0] = *(const f32x4*)&pp[q*8];
        *(f32x4*)&pr[4] = *(const f32x4*)&pp[q*8+4];
        const unsigned short* base = ptc + (size_t)q*6144;
        c0 += dot8(*(const uint4v*)(base + r0*8), pr);
        c1 += dot8(*(const uint4v*)(base + (r0+256)*8), pr);
        c2 += dot8(*(const uint4v*)(base + (r0+512)*8), pr);
      }
      par2[half*768 + r0]       = c0;
      par2[half*768 + r0 + 256] = c1;
      par2[half*768 + r0 + 512] = c2;
    }
    // no barrier: next step's B1 orders par2 writes before gate reads
    const float* tmp = hc; hc = hn; hn = (float*)tmp;
  }
}

extern "C" void kernel_launch(void* const* d_in, const int* in_sizes, int n_in,
                              void* d_out, int out_size, void* d_ws, size_t ws_size,
                              hipStream_t stream)
{
  (void)in_sizes; (void)n_in; (void)out_size;
  const int*   enc_in = (const int*)d_in[0];
  const int*   dec_in = (const int*)d_in[1];
  const float* embW   = (const float*)d_in[2];
  const float* Wi_f   = (const float*)d_in[3];
  const float* Wh_f   = (const float*)d_in[4];
  const float* bi_f   = (const float*)d_in[5];
  const float* bh_f   = (const float*)d_in[6];
  const float* Wi_b   = (const float*)d_in[7];
  const float* Wh_b   = (const float*)d_in[8];
  const float* bi_b   = (const float*)d_in[9];
  const float* bh_b   = (const float*)d_in[10];
  const float* Wi_d   = (const float*)d_in[11];
  const float* Wh_d   = (const float*)d_in[12];
  const float* bi_d   = (const float*)d_in[13];
  const float* bh_d   = (const float*)d_in[14];
  const float* W1_w   = (const float*)d_in[15];
  const float* W1_b   = (const float*)d_in[16];
  const float* W2_w   = (const float*)d_in[17];
  const float* W2_b   = (const float*)d_in[18];
  const float* lin_w  = (const float*)d_in[19];
  const float* lin_b  = (const float*)d_in[20];

  char* scr = (char*)d_out;
  float* emb_enc = (float*)(scr + 0);
  float* emb_dec = (float*)(scr + 4194304);
  float* gi_f    = (float*)(scr + 6291456);
  float* gi_b    = (float*)(scr + 18874368);
  float* gi_dx   = (float*)(scr + 31457280);
  float* enc     = (float*)(scr + 37748736);
  float* projf   = (float*)(scr + 46137344);
  unsigned short* whf_bf = (unsigned short*)(scr + 58720256);
  unsigned short* whb_bf = (unsigned short*)(scr + 59113472);
  unsigned short* whd_bf = (unsigned short*)(scr + 59506688);
  unsigned short* encw2  = (unsigned short*)(scr + 59899904);
  unsigned short* projt  = (unsigned short*)(scr + 61997056);
  float* encb2 = (float*)(scr + 68288512);
  int*   sizes = (int*)(scr + 68304896);
  float* h0    = (float*)(scr + 68305024);

  unsigned short* outs_bf = (unsigned short*)d_ws;
  unsigned short* lin_bf  = (unsigned short*)((char*)d_ws + (1<<20));
  const bool big = ws_size >= (size_t)(1<<20) + 16384000u + 1024u;

  // allow >64KB dynamic LDS for the decoder (capture-safe host attribute; idempotent)
  hipFuncSetAttribute((const void*)k_decoder, hipFuncAttributeMaxDynamicSharedMemorySize, 80384);

  k_sizes<<<1, 32, 0, stream>>>(enc_in, sizes);
  k_gather<<<Bb*TEe, 256, 0, stream>>>(enc_in, embW, emb_enc, Bb*TEe);
  k_gather<<<Bb*TDd, 256, 0, stream>>>(dec_in, embW, emb_dec, Bb*TDd);
  k_chunkw<<<768, 256, 0, stream>>>(Wh_f, whf_bf, 768);
  k_chunkw<<<768, 256, 0, stream>>>(Wh_b, whb_bf, 768);
  k_chunkw<<<768, 256, 0, stream>>>(Wh_d, whd_bf, 768);
  if (big) k_extract_bf16<<<32000, 256, 0, stream>>>(lin_w, lin_bf, 32000*256);

  k_gemm<false,false,false,false><<<dim3(6,32), 256, 0, stream>>>(
      emb_enc, Wi_f, bi_f, gi_f, 4096, 768, 256, 256, 256, 768);
  k_gemm<false,false,false,false><<<dim3(6,32), 256, 0, stream>>>(
      emb_enc, Wi_b, bi_b, gi_b, 4096, 768, 256, 256, 256, 768);
  k_gemm<false,false,false,false><<<dim3(6,16), 256, 0, stream>>>(
      emb_dec, Wi_d + 512, bi_d, gi_dx, 2048, 768, 256, 256, 768, 768);

  k_encoder<<<64, 512, 0, stream>>>(whf_bf, whb_bf, bh_f, bh_b, gi_f, gi_b, enc);
  k_encb2<<<Bb*TEe, 64, 0, stream>>>(enc, W2_b, encb2);

  k_gemm<false,false,true,true><<<dim3(2,32), 256, 0, stream>>>(
      enc, W2_w, nullptr, encw2, 4096, 256, 512, 512, 256, 256);
  k_gemm<false,false,false,false><<<dim3(6,32), 256, 0, stream>>>(
      enc, Wi_d, nullptr, projf, 4096, 768, 512, 512, 768, 768);
  k_projchunk<<<(Bb*16*768*8)/256, 256, 0, stream>>>(projf, projt);
  k_hinit<<<Bb, 256, 0, stream>>>(enc, sizes, W1_w, W1_b, h0);

  k_decoder<<<Bb, 512, 80384, stream>>>(whd_bf, bh_d, gi_dx, encw2, encb2, projt, h0, outs_bf);

  if (big)
    k_gemm<true,true,false,false><<<dim3(250,16), 256, 0, stream>>>(
        outs_bf, lin_bf, lin_b, d_out, 2048, 32000, 256, 256, 256, 32000);
  else
    k_gemm<true,false,false,false><<<dim3(250,16), 256, 0, stream>>>(
        outs_bf, lin_w, lin_b, d_out, 2048, 32000, 256, 256, 256, 32000);
}

// Round 6
// 5049.219 us; speedup vs baseline: 5.8211x; 1.0017x over previous
//
#include <hip/hip_runtime.h>
#include <hip/hip_bf16.h>

#define Vv 32000
#define Ee 256
#define Hh 256
#define Bb 32
#define TEe 128
#define TDd 64

typedef __attribute__((ext_vector_type(4))) float f32x4;
typedef __attribute__((ext_vector_type(8))) short short8;
typedef __attribute__((ext_vector_type(2))) unsigned int uint2v;
typedef __attribute__((ext_vector_type(4))) unsigned int uint4v;

static __device__ __forceinline__ unsigned short f2bf(float f){
  unsigned u = __float_as_uint(f);
  u += 0x7fffu + ((u >> 16) & 1u);           // round-to-nearest-even
  return (unsigned short)(u >> 16);
}
static __device__ __forceinline__ unsigned pack2(float a, float b){
  return ((unsigned)f2bf(b) << 16) | (unsigned)f2bf(a);
}
// dot of 8 packed bf16 (uint4) with 8 f32
static __device__ __forceinline__ float dot8(uint4v u, const float* hh){
  float s = 0.f;
  #pragma unroll
  for (int i = 0; i < 4; ++i){
    unsigned w = u[i];
    s = fmaf(__uint_as_float(w << 16),        hh[2*i],   s);
    s = fmaf(__uint_as_float(w & 0xffff0000u), hh[2*i+1], s);
  }
  return s;
}
static __device__ __forceinline__ float sigmoidf_(float x){
  return 1.f / (1.f + __expf(-x));
}

// ---------------- small prep kernels ----------------
__global__ void k_sizes(const int* __restrict__ enc_in, int* __restrict__ sizes){
  int b = threadIdx.x;
  if (b < Bb){
    int c = 0;
    for (int t = 0; t < TEe; ++t) c += (enc_in[b*TEe + t] > 0);
    sizes[b] = c;
  }
}

__global__ void k_gather(const int* __restrict__ tok, const float* __restrict__ embW,
                         float* __restrict__ out, int rows){
  int i = blockIdx.x * 256 + threadIdx.x;
  int r = i >> 8, c = i & 255;
  if (r < rows) out[i] = embW[(size_t)tok[r]*Ee + c];
}

// f32 -> bf16 row-major
__global__ void k_extract_bf16(const float* __restrict__ src, unsigned short* __restrict__ dst,
                               int n){
  int i = blockIdx.x * 256 + threadIdx.x;
  if (i < n) dst[i] = f2bf(src[i]);
}

// f32 [rows][256] -> chunked bf16 [32][rows][8]  (kb-major for coalesced staging)
__global__ void k_chunkw(const float* __restrict__ src, unsigned short* __restrict__ dst, int rows){
  int idx = blockIdx.x * 256 + threadIdx.x;
  if (idx < rows * 256){
    int i = idx & 7, r = (idx >> 3) % rows, kb = idx / (rows * 8);
    dst[idx] = f2bf(src[(size_t)r*256 + kb*8 + i]);
  }
}

// projf f32 [B*TE][768] -> chunked bf16 [B][16][768][8]
__global__ void k_projchunk(const float* __restrict__ in, unsigned short* __restrict__ out){
  int idx = blockIdx.x * 256 + threadIdx.x;     // total B*16*768*8
  int i = idx & 7;
  int t1 = idx >> 3;
  int n = t1 % 768;
  int t2 = t1 / 768;
  int kb = t2 & 15, b = t2 >> 4;
  out[idx] = f2bf(in[(size_t)(b*TEe + kb*8 + i)*768 + n]);
}

// ---------------- bf16 MFMA GEMM: C[M,N] = A[M,K] * B^T + bias ----------------
template<bool A_BF16, bool B_BF16, bool B_KMAJOR, bool OUT_BF16>
__global__ __launch_bounds__(256) void k_gemm(
  const void* __restrict__ Av, const void* __restrict__ Bv,
  const float* __restrict__ bias, void* __restrict__ Cv,
  int M, int N, int K, int lda, int ldb, int ldc)
{
  __shared__ unsigned short lA[128*40];
  __shared__ unsigned short lB[128*40];
  const int tid  = threadIdx.x;
  const int lane = tid & 63;
  const int w = tid >> 6, wr = w >> 1, wc = w & 1;
  const int m0 = blockIdx.y * 128, n0 = blockIdx.x * 128;
  f32x4 acc[4][4];
  #pragma unroll
  for (int i = 0; i < 4; ++i)
    #pragma unroll
    for (int j = 0; j < 4; ++j) acc[i][j] = (f32x4){0.f,0.f,0.f,0.f};

  for (int k0 = 0; k0 < K; k0 += 32){
    if (A_BF16){
      const unsigned short* A = (const unsigned short*)Av;
      #pragma unroll
      for (int it = 0; it < 2; ++it){
        int idx = tid + it*256; int r = idx >> 2, q = idx & 3;
        *(uint4v*)&lA[r*40 + q*8] = *(const uint4v*)(A + (size_t)(m0+r)*lda + k0 + q*8);
      }
    } else {
      const float* A = (const float*)Av;
      #pragma unroll
      for (int it = 0; it < 4; ++it){
        int idx = tid + it*256; int r = idx >> 3, q = idx & 7;
        f32x4 v = *(const f32x4*)(A + (size_t)(m0+r)*lda + k0 + q*4);
        uint2v pk; pk[0] = pack2(v[0], v[1]); pk[1] = pack2(v[2], v[3]);
        *(uint2v*)&lA[r*40 + q*4] = pk;
      }
    }
    if (B_KMAJOR){
      const float* Bp = (const float*)Bv;
      #pragma unroll
      for (int it = 0; it < 4; ++it){
        int idx = tid + it*256; int kk = idx >> 5, nq = idx & 31;
        f32x4 v = *(const f32x4*)(Bp + (size_t)(k0+kk)*ldb + n0 + nq*4);
        #pragma unroll
        for (int s2 = 0; s2 < 4; ++s2) lB[(nq*4+s2)*40 + kk] = f2bf(v[s2]);
      }
    } else if (B_BF16){
      const unsigned short* Bp = (const unsigned short*)Bv;
      #pragma unroll
      for (int it = 0; it < 2; ++it){
        int idx = tid + it*256; int r = idx >> 2, q = idx & 3;
        *(uint4v*)&lB[r*40 + q*8] = *(const uint4v*)(Bp + (size_t)(n0+r)*ldb + k0 + q*8);
      }
    } else {
      const float* Bp = (const float*)Bv;
      #pragma unroll
      for (int it = 0; it < 4; ++it){
        int idx = tid + it*256; int r = idx >> 3, q = idx & 7;
        f32x4 v = *(const f32x4*)(Bp + (size_t)(n0+r)*ldb + k0 + q*4);
        uint2v pk; pk[0] = pack2(v[0], v[1]); pk[1] = pack2(v[2], v[3]);
        *(uint2v*)&lB[r*40 + q*4] = pk;
      }
    }
    __syncthreads();
    short8 av[4], bv[4];
    #pragma unroll
    for (int i = 0; i < 4; ++i)
      av[i] = *(const short8*)&lA[(wr*64 + i*16 + (lane&15))*40 + (lane>>4)*8];
    #pragma unroll
    for (int j = 0; j < 4; ++j)
      bv[j] = *(const short8*)&lB[(wc*64 + j*16 + (lane&15))*40 + (lane>>4)*8];
    #pragma unroll
    for (int i = 0; i < 4; ++i)
      #pragma unroll
      for (int j = 0; j < 4; ++j)
        acc[i][j] = __builtin_amdgcn_mfma_f32_16x16x32_bf16(av[i], bv[j], acc[i][j], 0, 0, 0);
    __syncthreads();
  }
  #pragma unroll
  for (int i = 0; i < 4; ++i){
    #pragma unroll
    for (int j = 0; j < 4; ++j){
      int col = n0 + wc*64 + j*16 + (lane & 15);
      float bb = bias ? bias[col] : 0.f;
      #pragma unroll
      for (int r = 0; r < 4; ++r){
        int row = m0 + wr*64 + i*16 + (lane>>4)*4 + r;
        float v = acc[i][j][r] + bb;
        if (OUT_BF16) ((unsigned short*)Cv)[(size_t)row*ldc + col] = f2bf(v);
        else          ((float*)Cv)[(size_t)row*ldc + col] = v;
      }
    }
  }
}

// ---------------- encoder recurrence: 64 blocks = (dir, batch), 512 threads ----------------
// Thread T owns half (T>>8) of Wh rows {r0, r0+256, r0+512} in 48 uint4v = 192 VGPRs.
// __launch_bounds__(512, 1): arg2 is MIN BLOCKS PER CU (CUDA semantics — measured R5:
// arg2=2 capped VGPR at 128 and spilled the weight arrays). 1 block/CU -> 256-VGPR cap.
__global__ __launch_bounds__(512, 1) void k_encoder(
  const unsigned short* __restrict__ Whf, const unsigned short* __restrict__ Whb,
  const float* __restrict__ bhf, const float* __restrict__ bhb,
  const float* __restrict__ gif, const float* __restrict__ gib,
  float* __restrict__ encoded)
{
  __shared__ float hA[Hh], hB[Hh], par[1536];
  const int dir = blockIdx.x & 1, b = blockIdx.x >> 1;
  const unsigned short* Wh = dir ? Whb : Whf;
  const float* bh = dir ? bhb : bhf;
  const float* gi = dir ? gib : gif;
  const int T = threadIdx.x;
  const int half = T >> 8, r0 = T & 255;
  uint4v w0[16], w1[16], w2[16];
  #pragma unroll
  for (int q = 0; q < 16; ++q){
    const unsigned short* base = Wh + (size_t)(half*16 + q)*6144;
    w0[q] = *(const uint4v*)(base + r0*8);
    w1[q] = *(const uint4v*)(base + (r0+256)*8);
    w2[q] = *(const uint4v*)(base + (r0+512)*8);
  }
  float bh0 = 0.f, bh1 = 0.f, bh2 = 0.f;
  if (T < 256){ bh0 = bh[T]; bh1 = bh[T+256]; bh2 = bh[T+512]; hA[T] = 0.f; }
  __syncthreads();
  const float* hc = hA; float* hn = hB;
  for (int s = 0; s < TEe; ++s){
    const int t = dir ? (TEe-1-s) : s;
    float a0 = 0.f, a1 = 0.f, a2 = 0.f;
    const float* hh = hc + half*128;
    #pragma unroll
    for (int q = 0; q < 16; ++q){
      float hr[8];
      *(f32x4*)&hr[0] = *(const f32x4*)&hh[q*8];
      *(f32x4*)&hr[4] = *(const f32x4*)&hh[q*8+4];
      a0 += dot8(w0[q], hr);
      a1 += dot8(w1[q], hr);
      a2 += dot8(w2[q], hr);
    }
    par[half*768 + r0]       = a0;
    par[half*768 + r0 + 256] = a1;
    par[half*768 + r0 + 512] = a2;
    __syncthreads();                   // B1: partials ready
    if (T < 256){
      const float* grow = gi + (size_t)(b*TEe + t)*768;
      const float A0 = par[T]     + par[768+T]     + bh0;
      const float A1 = par[T+256] + par[768+T+256] + bh1;
      const float A2 = par[T+512] + par[768+T+512] + bh2;
      const float r = sigmoidf_(grow[T] + A0);
      const float z = sigmoidf_(grow[T+256] + A1);
      const float n = tanhf(grow[T+512] + r*A2);
      const float hnew = (1.f - z)*n + z*hc[T];
      hn[T] = hnew;
      encoded[(size_t)(b*TEe + t)*512 + dir*256 + T] = hnew;
    }
    __syncthreads();                   // B2: h_new visible; old hc fully consumed
    const float* tmp = hc; hc = hn; hn = (float*)tmp;
  }
}

// encb2[r] = encoded[r,:512] . W2_b
__global__ void k_encb2(const float* __restrict__ encoded, const float* __restrict__ W2b,
                        float* __restrict__ encb2){
  int r = blockIdx.x, l = threadIdx.x;
  const float* e = encoded + (size_t)r*512;
  float s = 0.f;
  for (int k = l; k < 512; k += 64) s += e[k]*W2b[k];
  for (int off = 32; off; off >>= 1) s += __shfl_down(s, off);
  if (l == 0) encb2[r] = s;
}

__global__ void k_hinit(const float* __restrict__ encoded, const int* __restrict__ sizes,
                        const float* __restrict__ W1w, const float* __restrict__ W1b,
                        float* __restrict__ h0){
  int b = blockIdx.x, o = threadIdx.x;
  int idx = sizes[b] - 1;
  idx = idx < 0 ? 0 : (idx > TEe-1 ? TEe-1 : idx);
  const float* ls = encoded + (size_t)(b*TEe + idx)*512;
  const float* wv = W1w + (size_t)o*512;
  float s = W1b[o];
  for (int k = 0; k < 512; k += 4){
    f32x4 a = *(const f32x4*)(ls + k);
    f32x4 w4 = *(const f32x4*)(wv + k);
    s = fmaf(a[0],w4[0], fmaf(a[1],w4[1], fmaf(a[2],w4[2], fmaf(a[3],w4[3], s))));
  }
  h0[b*256 + o] = s;
}

// ---------------- decoder: 32 blocks = batch, 512 threads ----------------
// Whd half-rows in registers (192 VGPR/thread); encw2[b] in LDS (64 KB, XOR-swizzled);
// projt streamed from L2 in ctx phase. launch_bounds(512,1) -> 256-VGPR cap (see encoder note).
// n-gate: ctx projection (gc) stays OUTSIDE the r* product (ref semantics).
__global__ __launch_bounds__(512, 1) void k_decoder(
  const unsigned short* __restrict__ Whd, const float* __restrict__ bhd,
  const float* __restrict__ gidx,            // [B][TD][768] f32 (includes bi_d)
  const unsigned short* __restrict__ encw2,  // [B*TE][256] bf16
  const float* __restrict__ encb2,           // [B*TE]
  const unsigned short* __restrict__ projt,  // [B][16][768][8] bf16
  const float* __restrict__ h0,
  unsigned short* __restrict__ outs_bf)      // [B][TD][256] bf16
{
  extern __shared__ char smem[];
  unsigned short* le = (unsigned short*)smem;      // 65536
  float* par  = (float*)(smem + 65536);            // 6144
  float* par2 = (float*)(smem + 71680);            // 6144
  float* hA   = (float*)(smem + 77824);            // 1024
  float* hB   = (float*)(smem + 78848);            // 1024
  float* p    = (float*)(smem + 79872);            // 512  -> total 80384
  const int b = blockIdx.x, T = threadIdx.x;
  const int half = T >> 8, r0 = T & 255;
  // stage encw2[b] (rows XOR-swizzled by k-chunk)
  for (int cc = T; cc < 128*32; cc += 512){
    int r = cc >> 5, q = cc & 31;
    *(uint4v*)&le[(r*32 + (q ^ (r & 31)))*8] =
        *(const uint4v*)(encw2 + ((size_t)(b*TEe + r) << 8) + (q << 3));
  }
  uint4v w0[16], w1[16], w2[16];
  #pragma unroll
  for (int q = 0; q < 16; ++q){
    const unsigned short* base = Whd + (size_t)(half*16 + q)*6144;
    w0[q] = *(const uint4v*)(base + r0*8);
    w1[q] = *(const uint4v*)(base + (r0+256)*8);
    w2[q] = *(const uint4v*)(base + (r0+512)*8);
  }
  const unsigned short* ptc = projt + (size_t)b*98304 + (size_t)half*8*6144;
  const float eb = encb2[b*TEe + (T >> 2)];
  float bh0 = 0.f, bh1 = 0.f, bh2 = 0.f;
  if (T < 256){
    bh0 = bhd[T]; bh1 = bhd[T+256]; bh2 = bhd[T+512];
    hA[T] = h0[b*256 + T];
  }
  par2[T] = 0.f; par2[T+512] = 0.f; par2[T+1024] = 0.f;   // ctx_init = 0
  __syncthreads();
  const float* hc = hA; float* hn = hB;
  for (int t = 0; t < TDd; ++t){
    // phase 1: GRU partial dots from register weights
    {
      float a0 = 0.f, a1 = 0.f, a2 = 0.f;
      const float* hh = hc + half*128;
      #pragma unroll
      for (int q = 0; q < 16; ++q){
        float hr[8];
        *(f32x4*)&hr[0] = *(const f32x4*)&hh[q*8];
        *(f32x4*)&hr[4] = *(const f32x4*)&hh[q*8+4];
        a0 += dot8(w0[q], hr);
        a1 += dot8(w1[q], hr);
        a2 += dot8(w2[q], hr);
      }
      par[half*768 + r0]       = a0;
      par[half*768 + r0 + 256] = a1;
      par[half*768 + r0 + 512] = a2;
    }
    __syncthreads();                   // B1
    if (T < 256){
      const float* grow = gidx + (size_t)(b*TDd + t)*768;
      const float A0 = par[T]     + par[768+T]     + bh0;
      const float A1 = par[T+256] + par[768+T+256] + bh1;
      const float A2 = par[T+512] + par[768+T+512] + bh2;
      const float gc0 = par2[T]     + par2[768+T];
      const float gc1 = par2[T+256] + par2[768+T+256];
      const float gc2 = par2[T+512] + par2[768+T+512];
      const float r = sigmoidf_(grow[T] + gc0 + A0);
      const float z = sigmoidf_(grow[T+256] + gc1 + A1);
      const float n = tanhf(grow[T+512] + gc2 + r*A2);
      const float hnew = (1.f - z)*n + z*hc[T];
      hn[T] = hnew;
      outs_bf[(size_t)(b*TDd + t)*256 + T] = f2bf(hnew);
    }
    __syncthreads();                   // B2: h_new visible
    // phase 3: scores from LDS encw2, 4-thread k-split per row
    {
      const int tt = T >> 2, l = T & 3, tx = tt & 31;
      const unsigned short* er = le + tt*256;
      const float* hh = hn + l*64;
      float s = 0.f;
      #pragma unroll
      for (int i = 0; i < 8; ++i){
        const int q = l*8 + i;
        float hr[8];
        *(f32x4*)&hr[0] = *(const f32x4*)&hh[i*8];
        *(f32x4*)&hr[4] = *(const f32x4*)&hh[i*8+4];
        s += dot8(*(const uint4v*)(er + ((q ^ tx) << 3)), hr);
      }
      s += __shfl_xor(s, 1);
      s += __shfl_xor(s, 2);
      if (l == 0) p[tt] = s + eb;
    }
    __syncthreads();                   // B3
    if (T < 64){
      float m = fmaxf(p[T], p[T+64]);
      for (int off = 32; off; off >>= 1) m = fmaxf(m, __shfl_xor(m, off));
      float e0 = __expf(p[T] - m), e1 = __expf(p[T+64] - m);
      float ss = e0 + e1;
      for (int off = 32; off; off >>= 1) ss += __shfl_xor(ss, off);
      float inv = 1.f / ss;
      p[T] = e0*inv; p[T+64] = e1*inv;
    }
    __syncthreads();                   // B4: softmax done
    // phase 5: ctx projection partials (projt streamed from L2)
    {
      float c0 = 0.f, c1 = 0.f, c2 = 0.f;
      const float* pp = p + half*64;
      #pragma unroll
      for (int q = 0; q < 8; ++q){
        float pr[8];
        *(f32x4*)&pr[0] = *(const f32x4*)&pp[q*8];
        *(f32x4*)&pr[4] = *(const f32x4*)&pp[q*8+4];
        const unsigned short* base = ptc + (size_t)q*6144;
        c0 += dot8(*(const uint4v*)(base + r0*8), pr);
        c1 += dot8(*(const uint4v*)(base + (r0+256)*8), pr);
        c2 += dot8(*(const uint4v*)(base + (r0+512)*8), pr);
      }
      par2[half*768 + r0]       = c0;
      par2[half*768 + r0 + 256] = c1;
      par2[half*768 + r0 + 512] = c2;
    }
    // no barrier: next step's B1 orders par2 writes before gate reads
    const float* tmp = hc; hc = hn; hn = (float*)tmp;
  }
}

extern "C" void kernel_launch(void* const* d_in, const int* in_sizes, int n_in,
                              void* d_out, int out_size, void* d_ws, size_t ws_size,
                              hipStream_t stream)
{
  (void)in_sizes; (void)n_in; (void)out_size;
  const int*   enc_in = (const int*)d_in[0];
  const int*   dec_in = (const int*)d_in[1];
  const float* embW   = (const float*)d_in[2];
  const float* Wi_f   = (const float*)d_in[3];
  const float* Wh_f   = (const float*)d_in[4];
  const float* bi_f   = (const float*)d_in[5];
  const float* bh_f   = (const float*)d_in[6];
  const float* Wi_b   = (const float*)d_in[7];
  const float* Wh_b   = (const float*)d_in[8];
  const float* bi_b   = (const float*)d_in[9];
  const float* bh_b   = (const float*)d_in[10];
  const float* Wi_d   = (const float*)d_in[11];
  const float* Wh_d   = (const float*)d_in[12];
  const float* bi_d   = (const float*)d_in[13];
  const float* bh_d   = (const float*)d_in[14];
  const float* W1_w   = (const float*)d_in[15];
  const float* W1_b   = (const float*)d_in[16];
  const float* W2_w   = (const float*)d_in[17];
  const float* W2_b   = (const float*)d_in[18];
  const float* lin_w  = (const float*)d_in[19];
  const float* lin_b  = (const float*)d_in[20];

  char* scr = (char*)d_out;
  float* emb_enc = (float*)(scr + 0);
  float* emb_dec = (float*)(scr + 4194304);
  float* gi_f    = (float*)(scr + 6291456);
  float* gi_b    = (float*)(scr + 18874368);
  float* gi_dx   = (float*)(scr + 31457280);
  float* enc     = (float*)(scr + 37748736);
  float* projf   = (float*)(scr + 46137344);
  unsigned short* whf_bf = (unsigned short*)(scr + 58720256);
  unsigned short* whb_bf = (unsigned short*)(scr + 59113472);
  unsigned short* whd_bf = (unsigned short*)(scr + 59506688);
  unsigned short* encw2  = (unsigned short*)(scr + 59899904);
  unsigned short* projt  = (unsigned short*)(scr + 61997056);
  float* encb2 = (float*)(scr + 68288512);
  int*   sizes = (int*)(scr + 68304896);
  float* h0    = (float*)(scr + 68305024);

  unsigned short* outs_bf = (unsigned short*)d_ws;
  unsigned short* lin_bf  = (unsigned short*)((char*)d_ws + (1<<20));
  const bool big = ws_size >= (size_t)(1<<20) + 16384000u + 1024u;

  // allow >64KB dynamic LDS for the decoder (capture-safe host attribute; idempotent)
  hipFuncSetAttribute((const void*)k_decoder, hipFuncAttributeMaxDynamicSharedMemorySize, 80384);

  k_sizes<<<1, 32, 0, stream>>>(enc_in, sizes);
  k_gather<<<Bb*TEe, 256, 0, stream>>>(enc_in, embW, emb_enc, Bb*TEe);
  k_gather<<<Bb*TDd, 256, 0, stream>>>(dec_in, embW, emb_dec, Bb*TDd);
  k_chunkw<<<768, 256, 0, stream>>>(Wh_f, whf_bf, 768);
  k_chunkw<<<768, 256, 0, stream>>>(Wh_b, whb_bf, 768);
  k_chunkw<<<768, 256, 0, stream>>>(Wh_d, whd_bf, 768);
  if (big) k_extract_bf16<<<32000, 256, 0, stream>>>(lin_w, lin_bf, 32000*256);

  k_gemm<false,false,false,false><<<dim3(6,32), 256, 0, stream>>>(
      emb_enc, Wi_f, bi_f, gi_f, 4096, 768, 256, 256, 256, 768);
  k_gemm<false,false,false,false><<<dim3(6,32), 256, 0, stream>>>(
      emb_enc, Wi_b, bi_b, gi_b, 4096, 768, 256, 256, 256, 768);
  k_gemm<false,false,false,false><<<dim3(6,16), 256, 0, stream>>>(
      emb_dec, Wi_d + 512, bi_d, gi_dx, 2048, 768, 256, 256, 768, 768);

  k_encoder<<<64, 512, 0, stream>>>(whf_bf, whb_bf, bh_f, bh_b, gi_f, gi_b, enc);
  k_encb2<<<Bb*TEe, 64, 0, stream>>>(enc, W2_b, encb2);

  k_gemm<false,false,true,true><<<dim3(2,32), 256, 0, stream>>>(
      enc, W2_w, nullptr, encw2, 4096, 256, 512, 512, 256, 256);
  k_gemm<false,false,false,false><<<dim3(6,32), 256, 0, stream>>>(
      enc, Wi_d, nullptr, projf, 4096, 768, 512, 512, 768, 768);
  k_projchunk<<<(Bb*16*768*8)/256, 256, 0, stream>>>(projf, projt);
  k_hinit<<<Bb, 256, 0, stream>>>(enc, sizes, W1_w, W1_b, h0);

  k_decoder<<<Bb, 512, 80384, stream>>>(whd_bf, bh_d, gi_dx, encw2, encb2, projt, h0, outs_bf);

  if (big)
    k_gemm<true,true,false,false><<<dim3(250,16), 256, 0, stream>>>(
        outs_bf, lin_bf, lin_b, d_out, 2048, 32000, 256, 256, 256, 32000);
  else
    k_gemm<true,false,false,false><<<dim3(250,16), 256, 0, stream>>>(
        outs_bf, lin_w, lin_b, d_out, 2048, 32000, 256, 256, 256, 32000);
}

// Round 7
// 2172.021 us; speedup vs baseline: 13.5320x; 2.3247x over previous
//
#include <hip/hip_runtime.h>
#include <hip/hip_bf16.h>

#define Vv 32000
#define Ee 256
#define Hh 256
#define Bb 32
#define TEe 128
#define TDd 64

typedef __attribute__((ext_vector_type(4))) float f32x4;
typedef __attribute__((ext_vector_type(8))) short short8;
typedef __attribute__((ext_vector_type(2))) unsigned int uint2v;
typedef __attribute__((ext_vector_type(4))) unsigned int uint4v;

static __device__ __forceinline__ unsigned short f2bf(float f){
  unsigned u = __float_as_uint(f);
  u += 0x7fffu + ((u >> 16) & 1u);           // round-to-nearest-even
  return (unsigned short)(u >> 16);
}
static __device__ __forceinline__ unsigned pack2(float a, float b){
  return ((unsigned)f2bf(b) << 16) | (unsigned)f2bf(a);
}
// dot of 8 packed bf16 (uint4) with 8 f32
static __device__ __forceinline__ float dot8(uint4v u, const float* hh){
  float s = 0.f;
  #pragma unroll
  for (int i = 0; i < 4; ++i){
    unsigned w = u[i];
    s = fmaf(__uint_as_float(w << 16),        hh[2*i],   s);
    s = fmaf(__uint_as_float(w & 0xffff0000u), hh[2*i+1], s);
  }
  return s;
}
static __device__ __forceinline__ float sigmoidf_(float x){
  return 1.f / (1.f + __expf(-x));
}

// ---------------- small prep kernels ----------------
__global__ void k_sizes(const int* __restrict__ enc_in, int* __restrict__ sizes){
  int b = threadIdx.x;
  if (b < Bb){
    int c = 0;
    for (int t = 0; t < TEe; ++t) c += (enc_in[b*TEe + t] > 0);
    sizes[b] = c;
  }
}

__global__ void k_gather(const int* __restrict__ tok, const float* __restrict__ embW,
                         float* __restrict__ out, int rows){
  int i = blockIdx.x * 256 + threadIdx.x;
  int r = i >> 8, c = i & 255;
  if (r < rows) out[i] = embW[(size_t)tok[r]*Ee + c];
}

// f32 -> bf16 row-major
__global__ void k_extract_bf16(const float* __restrict__ src, unsigned short* __restrict__ dst,
                               int n){
  int i = blockIdx.x * 256 + threadIdx.x;
  if (i < n) dst[i] = f2bf(src[i]);
}

// f32 [rows][256] -> chunked bf16 [32][rows][8]  (kb-major for coalesced staging)
__global__ void k_chunkw(const float* __restrict__ src, unsigned short* __restrict__ dst, int rows){
  int idx = blockIdx.x * 256 + threadIdx.x;
  if (idx < rows * 256){
    int i = idx & 7, r = (idx >> 3) % rows, kb = idx / (rows * 8);
    dst[idx] = f2bf(src[(size_t)r*256 + kb*8 + i]);
  }
}

// projf f32 [B*TE][768] -> chunked bf16 [B][16][768][8]
__global__ void k_projchunk(const float* __restrict__ in, unsigned short* __restrict__ out){
  int idx = blockIdx.x * 256 + threadIdx.x;     // total B*16*768*8
  int i = idx & 7;
  int t1 = idx >> 3;
  int n = t1 % 768;
  int t2 = t1 / 768;
  int kb = t2 & 15, b = t2 >> 4;
  out[idx] = f2bf(in[(size_t)(b*TEe + kb*8 + i)*768 + n]);
}

// ---------------- bf16 MFMA GEMM: C[M,N] = A[M,K] * B^T + bias ----------------
template<bool A_BF16, bool B_BF16, bool B_KMAJOR, bool OUT_BF16>
__global__ __launch_bounds__(256) void k_gemm(
  const void* __restrict__ Av, const void* __restrict__ Bv,
  const float* __restrict__ bias, void* __restrict__ Cv,
  int M, int N, int K, int lda, int ldb, int ldc)
{
  __shared__ unsigned short lA[128*40];
  __shared__ unsigned short lB[128*40];
  const int tid  = threadIdx.x;
  const int lane = tid & 63;
  const int w = tid >> 6, wr = w >> 1, wc = w & 1;
  const int m0 = blockIdx.y * 128, n0 = blockIdx.x * 128;
  f32x4 acc[4][4];
  #pragma unroll
  for (int i = 0; i < 4; ++i)
    #pragma unroll
    for (int j = 0; j < 4; ++j) acc[i][j] = (f32x4){0.f,0.f,0.f,0.f};

  for (int k0 = 0; k0 < K; k0 += 32){
    if (A_BF16){
      const unsigned short* A = (const unsigned short*)Av;
      #pragma unroll
      for (int it = 0; it < 2; ++it){
        int idx = tid + it*256; int r = idx >> 2, q = idx & 3;
        *(uint4v*)&lA[r*40 + q*8] = *(const uint4v*)(A + (size_t)(m0+r)*lda + k0 + q*8);
      }
    } else {
      const float* A = (const float*)Av;
      #pragma unroll
      for (int it = 0; it < 4; ++it){
        int idx = tid + it*256; int r = idx >> 3, q = idx & 7;
        f32x4 v = *(const f32x4*)(A + (size_t)(m0+r)*lda + k0 + q*4);
        uint2v pk; pk[0] = pack2(v[0], v[1]); pk[1] = pack2(v[2], v[3]);
        *(uint2v*)&lA[r*40 + q*4] = pk;
      }
    }
    if (B_KMAJOR){
      const float* Bp = (const float*)Bv;
      #pragma unroll
      for (int it = 0; it < 4; ++it){
        int idx = tid + it*256; int kk = idx >> 5, nq = idx & 31;
        f32x4 v = *(const f32x4*)(Bp + (size_t)(k0+kk)*ldb + n0 + nq*4);
        #pragma unroll
        for (int s2 = 0; s2 < 4; ++s2) lB[(nq*4+s2)*40 + kk] = f2bf(v[s2]);
      }
    } else if (B_BF16){
      const unsigned short* Bp = (const unsigned short*)Bv;
      #pragma unroll
      for (int it = 0; it < 2; ++it){
        int idx = tid + it*256; int r = idx >> 2, q = idx & 3;
        *(uint4v*)&lB[r*40 + q*8] = *(const uint4v*)(Bp + (size_t)(n0+r)*ldb + k0 + q*8);
      }
    } else {
      const float* Bp = (const float*)Bv;
      #pragma unroll
      for (int it = 0; it < 4; ++it){
        int idx = tid + it*256; int r = idx >> 3, q = idx & 7;
        f32x4 v = *(const f32x4*)(Bp + (size_t)(n0+r)*ldb + k0 + q*4);
        uint2v pk; pk[0] = pack2(v[0], v[1]); pk[1] = pack2(v[2], v[3]);
        *(uint2v*)&lB[r*40 + q*4] = pk;
      }
    }
    __syncthreads();
    short8 av[4], bv[4];
    #pragma unroll
    for (int i = 0; i < 4; ++i)
      av[i] = *(const short8*)&lA[(wr*64 + i*16 + (lane&15))*40 + (lane>>4)*8];
    #pragma unroll
    for (int j = 0; j < 4; ++j)
      bv[j] = *(const short8*)&lB[(wc*64 + j*16 + (lane&15))*40 + (lane>>4)*8];
    #pragma unroll
    for (int i = 0; i < 4; ++i)
      #pragma unroll
      for (int j = 0; j < 4; ++j)
        acc[i][j] = __builtin_amdgcn_mfma_f32_16x16x32_bf16(av[i], bv[j], acc[i][j], 0, 0, 0);
    __syncthreads();
  }
  #pragma unroll
  for (int i = 0; i < 4; ++i){
    #pragma unroll
    for (int j = 0; j < 4; ++j){
      int col = n0 + wc*64 + j*16 + (lane & 15);
      float bb = bias ? bias[col] : 0.f;
      #pragma unroll
      for (int r = 0; r < 4; ++r){
        int row = m0 + wr*64 + i*16 + (lane>>4)*4 + r;
        float v = acc[i][j][r] + bb;
        if (OUT_BF16) ((unsigned short*)Cv)[(size_t)row*ldc + col] = f2bf(v);
        else          ((float*)Cv)[(size_t)row*ldc + col] = v;
      }
    }
  }
}

// ---------------- encoder recurrence: 64 blocks = (dir, batch), 1024 threads ----------------
// Weight split sized for the 128-VGPR cap (4 waves/EU is forced at 1024 thr):
//   rows 0-255   -> LDS (131 KB, chunk-swizzled), read as quarter-rows (4 partials)
//   rows 256-767 -> registers: thread T holds HALF of row 256+(T&511), half=T>>9
//                   = 16 uint4v = 64 VGPR (total demand ~100 < 128 -> no spill/remat)
__global__ __launch_bounds__(1024) void k_encoder(
  const unsigned short* __restrict__ Whf, const unsigned short* __restrict__ Whb,
  const float* __restrict__ bhf, const float* __restrict__ bhb,
  const float* __restrict__ gif, const float* __restrict__ gib,
  float* __restrict__ encoded)
{
  extern __shared__ char smem[];
  unsigned short* lw = (unsigned short*)smem;        // 131072
  float* hA   = (float*)(smem + 131072);             // 1024
  float* hB   = (float*)(smem + 132096);             // 1024
  float* parA = (float*)(smem + 133120);             // 4096 (4 quarters x 256 rows)
  float* parB = (float*)(smem + 137216);             // 4096 (2 halves x 512 rows)
  const int dir = blockIdx.x & 1, b = blockIdx.x >> 1;
  const unsigned short* Wh = dir ? Whb : Whf;
  const float* bh = dir ? bhb : bhf;
  const float* gi = dir ? gib : gif;
  const int T = threadIdx.x;
  const int rl = T & 255, q4 = T >> 8;               // LDS-part task
  const int rrh = T & 511, hf = T >> 9;              // reg-part task (row 256+rrh, half hf)
  // stage LDS rows 0-255 (chunk-swizzled)
  for (int cc = T; cc < 256*32; cc += 1024){
    int r = cc >> 5, q = cc & 31;
    *(uint4v*)&lw[(r*32 + (q ^ (r & 31)))*8] = *(const uint4v*)(Wh + (size_t)q*6144 + r*8);
  }
  // register half-row
  uint4v wr_[16];
  #pragma unroll
  for (int q = 0; q < 16; ++q)
    wr_[q] = *(const uint4v*)(Wh + (size_t)(hf*16 + q)*6144 + (256 + rrh)*8);
  float bh0 = 0.f, bh1 = 0.f, bh2 = 0.f;
  if (T < 256){ bh0 = bh[T]; bh1 = bh[T+256]; bh2 = bh[T+512]; hA[T] = 0.f; }
  __syncthreads();
  const float* hc = hA; float* hn = hB;
  for (int s = 0; s < TEe; ++s){
    const int t = dir ? (TEe-1-s) : s;
    // LDS-part: quarter q4 of row rl
    float aL = 0.f;
    #pragma unroll
    for (int i = 0; i < 8; ++i){
      const int ck = q4*8 + i;
      float hr[8];
      *(f32x4*)&hr[0] = *(const f32x4*)&hc[ck*8];
      *(f32x4*)&hr[4] = *(const f32x4*)&hc[ck*8+4];
      aL += dot8(*(const uint4v*)&lw[(rl*32 + (ck ^ (rl & 31)))*8], hr);
    }
    parA[q4*256 + rl] = aL;
    // reg-part: half hf of row 256+rrh
    float aR = 0.f;
    const float* hh = hc + hf*128;
    #pragma unroll
    for (int q = 0; q < 16; ++q){
      float hr[8];
      *(f32x4*)&hr[0] = *(const f32x4*)&hh[q*8];
      *(f32x4*)&hr[4] = *(const f32x4*)&hh[q*8+4];
      aR += dot8(wr_[q], hr);
    }
    parB[hf*512 + rrh] = aR;
    __syncthreads();                   // B1: partials ready
    if (T < 256){
      const int j = T;
      const float* grow = gi + (size_t)(b*TEe + t)*768;
      const float A0 = parA[j] + parA[256+j] + parA[512+j] + parA[768+j] + bh0;
      const float A1 = parB[j] + parB[512+j] + bh1;
      const float A2 = parB[256+j] + parB[768+j] + bh2;
      const float r = sigmoidf_(grow[j] + A0);
      const float z = sigmoidf_(grow[j+256] + A1);
      const float n = tanhf(grow[j+512] + r*A2);
      const float hnew = (1.f - z)*n + z*hc[j];
      hn[j] = hnew;
      encoded[(size_t)(b*TEe + t)*512 + dir*256 + j] = hnew;
    }
    __syncthreads();                   // B2: h_new visible
    const float* tmp = hc; hc = hn; hn = (float*)tmp;
  }
}

// encb2[r] = encoded[r,:512] . W2_b
__global__ void k_encb2(const float* __restrict__ encoded, const float* __restrict__ W2b,
                        float* __restrict__ encb2){
  int r = blockIdx.x, l = threadIdx.x;
  const float* e = encoded + (size_t)r*512;
  float s = 0.f;
  for (int k = l; k < 512; k += 64) s += e[k]*W2b[k];
  for (int off = 32; off; off >>= 1) s += __shfl_down(s, off);
  if (l == 0) encb2[r] = s;
}

__global__ void k_hinit(const float* __restrict__ encoded, const int* __restrict__ sizes,
                        const float* __restrict__ W1w, const float* __restrict__ W1b,
                        float* __restrict__ h0){
  int b = blockIdx.x, o = threadIdx.x;
  int idx = sizes[b] - 1;
  idx = idx < 0 ? 0 : (idx > TEe-1 ? TEe-1 : idx);
  const float* ls = encoded + (size_t)(b*TEe + idx)*512;
  const float* wv = W1w + (size_t)o*512;
  float s = W1b[o];
  for (int k = 0; k < 512; k += 4){
    f32x4 a = *(const f32x4*)(ls + k);
    f32x4 w4 = *(const f32x4*)(wv + k);
    s = fmaf(a[0],w4[0], fmaf(a[1],w4[1], fmaf(a[2],w4[2], fmaf(a[3],w4[3], s))));
  }
  h0[b*256 + o] = s;
}

// ---------------- decoder: 32 blocks = batch, 1024 threads ----------------
// GRU phase = encoder structure (Whd rows 0-255 LDS / 256-767 reg half-rows).
// Scores: encw2 streamed from L2, 8 threads per row + shuffle reduce.
// Ctx: projt streamed from L2, thread T<768 computes its full gc row.
// n-gate: ctx projection stays OUTSIDE the r* product (ref semantics).
__global__ __launch_bounds__(1024) void k_decoder(
  const unsigned short* __restrict__ Whd, const float* __restrict__ bhd,
  const float* __restrict__ gidx,            // [B][TD][768] f32 (includes bi_d)
  const unsigned short* __restrict__ encw2,  // [B*TE][256] bf16
  const float* __restrict__ encb2,           // [B*TE]
  const unsigned short* __restrict__ projt,  // [B][16][768][8] bf16
  const float* __restrict__ h0,
  unsigned short* __restrict__ outs_bf)      // [B][TD][256] bf16
{
  extern __shared__ char smem[];
  unsigned short* lw = (unsigned short*)smem;        // 131072
  float* hA   = (float*)(smem + 131072);             // 1024
  float* hB   = (float*)(smem + 132096);             // 1024
  float* parA = (float*)(smem + 133120);             // 4096
  float* parB = (float*)(smem + 137216);             // 4096
  float* p    = (float*)(smem + 141312);             // 512
  float* gcs  = (float*)(smem + 141824);             // 3072 -> total 144896
  const int b = blockIdx.x, T = threadIdx.x;
  const int rl = T & 255, q4 = T >> 8;
  const int rrh = T & 511, hf = T >> 9;
  for (int cc = T; cc < 256*32; cc += 1024){
    int r = cc >> 5, q = cc & 31;
    *(uint4v*)&lw[(r*32 + (q ^ (r & 31)))*8] = *(const uint4v*)(Whd + (size_t)q*6144 + r*8);
  }
  uint4v wr_[16];
  #pragma unroll
  for (int q = 0; q < 16; ++q)
    wr_[q] = *(const uint4v*)(Whd + (size_t)(hf*16 + q)*6144 + (256 + rrh)*8);
  const unsigned short* ptc = projt + (size_t)b*98304;
  const unsigned short* erow = encw2 + ((size_t)(b*TEe + (T >> 3)) << 8) + (T & 7)*32;
  const float eb = encb2[b*TEe + (T >> 3)];
  float bh0 = 0.f, bh1 = 0.f, bh2 = 0.f;
  if (T < 256){
    bh0 = bhd[T]; bh1 = bhd[T+256]; bh2 = bhd[T+512];
    hA[T] = h0[b*256 + T];
  }
  if (T < 768) gcs[T] = 0.f;           // ctx_init = 0
  __syncthreads();
  const float* hc = hA; float* hn = hB;
  for (int t = 0; t < TDd; ++t){
    // phase 1: GRU dots (LDS quarter + register half)
    float aL = 0.f;
    #pragma unroll
    for (int i = 0; i < 8; ++i){
      const int ck = q4*8 + i;
      float hr[8];
      *(f32x4*)&hr[0] = *(const f32x4*)&hc[ck*8];
      *(f32x4*)&hr[4] = *(const f32x4*)&hc[ck*8+4];
      aL += dot8(*(const uint4v*)&lw[(rl*32 + (ck ^ (rl & 31)))*8], hr);
    }
    parA[q4*256 + rl] = aL;
    float aR = 0.f;
    const float* hh = hc + hf*128;
    #pragma unroll
    for (int q = 0; q < 16; ++q){
      float hr[8];
      *(f32x4*)&hr[0] = *(const f32x4*)&hh[q*8];
      *(f32x4*)&hr[4] = *(const f32x4*)&hh[q*8+4];
      aR += dot8(wr_[q], hr);
    }
    parB[hf*512 + rrh] = aR;
    __syncthreads();                   // B1
    if (T < 256){
      const int j = T;
      const float* grow = gidx + (size_t)(b*TDd + t)*768;
      const float A0 = parA[j] + parA[256+j] + parA[512+j] + parA[768+j] + bh0;
      const float A1 = parB[j] + parB[512+j] + bh1;
      const float A2 = parB[256+j] + parB[768+j] + bh2;
      const float r = sigmoidf_(grow[j] + gcs[j] + A0);
      const float z = sigmoidf_(grow[j+256] + gcs[j+256] + A1);
      const float n = tanhf(grow[j+512] + gcs[j+512] + r*A2);
      const float hnew = (1.f - z)*n + z*hc[j];
      hn[j] = hnew;
      outs_bf[(size_t)(b*TDd + t)*256 + j] = f2bf(hnew);
    }
    __syncthreads();                   // B2: h_new visible
    // phase 3: scores — 8 threads per enc position, encw2 streamed (coalesced)
    {
      const int oct = T & 7;
      const float* hh = hn + oct*32;
      float s = 0.f;
      #pragma unroll
      for (int i = 0; i < 4; ++i){
        float hr[8];
        *(f32x4*)&hr[0] = *(const f32x4*)&hh[i*8];
        *(f32x4*)&hr[4] = *(const f32x4*)&hh[i*8+4];
        s += dot8(*(const uint4v*)(erow + i*8), hr);
      }
      s += __shfl_xor(s, 1);
      s += __shfl_xor(s, 2);
      s += __shfl_xor(s, 4);
      if (oct == 0) p[T >> 3] = s + eb;
    }
    __syncthreads();                   // B3
    if (T < 64){
      float m = fmaxf(p[T], p[T+64]);
      for (int off = 32; off; off >>= 1) m = fmaxf(m, __shfl_xor(m, off));
      float e0 = __expf(p[T] - m), e1 = __expf(p[T+64] - m);
      float ss = e0 + e1;
      for (int off = 32; off; off >>= 1) ss += __shfl_xor(ss, off);
      float inv = 1.f / ss;
      p[T] = e0*inv; p[T+64] = e1*inv;
    }
    __syncthreads();                   // B4: softmax done
    // phase 5: ctx projection — thread T<768 computes its full row over 128 enc pos
    if (T < 768){
      float c = 0.f;
      #pragma unroll
      for (int q = 0; q < 16; ++q){
        float pr[8];
        *(f32x4*)&pr[0] = *(const f32x4*)&p[q*8];
        *(f32x4*)&pr[4] = *(const f32x4*)&p[q*8+4];
        c += dot8(*(const uint4v*)(ptc + (size_t)q*6144 + T*8), pr);
      }
      gcs[T] = c;
    }
    // no barrier: next step's B1 orders gcs writes before gate reads,
    // and p is only rewritten after next step's B2/B3.
    const float* tmp = hc; hc = hn; hn = (float*)tmp;
  }
}

extern "C" void kernel_launch(void* const* d_in, const int* in_sizes, int n_in,
                              void* d_out, int out_size, void* d_ws, size_t ws_size,
                              hipStream_t stream)
{
  (void)in_sizes; (void)n_in; (void)out_size;
  const int*   enc_in = (const int*)d_in[0];
  const int*   dec_in = (const int*)d_in[1];
  const float* embW   = (const float*)d_in[2];
  const float* Wi_f   = (const float*)d_in[3];
  const float* Wh_f   = (const float*)d_in[4];
  const float* bi_f   = (const float*)d_in[5];
  const float* bh_f   = (const float*)d_in[6];
  const float* Wi_b   = (const float*)d_in[7];
  const float* Wh_b   = (const float*)d_in[8];
  const float* bi_b   = (const float*)d_in[9];
  const float* bh_b   = (const float*)d_in[10];
  const float* Wi_d   = (const float*)d_in[11];
  const float* Wh_d   = (const float*)d_in[12];
  const float* bi_d   = (const float*)d_in[13];
  const float* bh_d   = (const float*)d_in[14];
  const float* W1_w   = (const float*)d_in[15];
  const float* W1_b   = (const float*)d_in[16];
  const float* W2_w   = (const float*)d_in[17];
  const float* W2_b   = (const float*)d_in[18];
  const float* lin_w  = (const float*)d_in[19];
  const float* lin_b  = (const float*)d_in[20];

  char* scr = (char*)d_out;
  float* emb_enc = (float*)(scr + 0);
  float* emb_dec = (float*)(scr + 4194304);
  float* gi_f    = (float*)(scr + 6291456);
  float* gi_b    = (float*)(scr + 18874368);
  float* gi_dx   = (float*)(scr + 31457280);
  float* enc     = (float*)(scr + 37748736);
  float* projf   = (float*)(scr + 46137344);
  unsigned short* whf_bf = (unsigned short*)(scr + 58720256);
  unsigned short* whb_bf = (unsigned short*)(scr + 59113472);
  unsigned short* whd_bf = (unsigned short*)(scr + 59506688);
  unsigned short* encw2  = (unsigned short*)(scr + 59899904);
  unsigned short* projt  = (unsigned short*)(scr + 61997056);
  float* encb2 = (float*)(scr + 68288512);
  int*   sizes = (int*)(scr + 68304896);
  float* h0    = (float*)(scr + 68305024);

  unsigned short* outs_bf = (unsigned short*)d_ws;
  unsigned short* lin_bf  = (unsigned short*)((char*)d_ws + (1<<20));
  const bool big = ws_size >= (size_t)(1<<20) + 16384000u + 1024u;

  // allow >64KB dynamic LDS (capture-safe host attribute; idempotent)
  hipFuncSetAttribute((const void*)k_encoder, hipFuncAttributeMaxDynamicSharedMemorySize, 141312);
  hipFuncSetAttribute((const void*)k_decoder, hipFuncAttributeMaxDynamicSharedMemorySize, 144896);

  k_sizes<<<1, 32, 0, stream>>>(enc_in, sizes);
  k_gather<<<Bb*TEe, 256, 0, stream>>>(enc_in, embW, emb_enc, Bb*TEe);
  k_gather<<<Bb*TDd, 256, 0, stream>>>(dec_in, embW, emb_dec, Bb*TDd);
  k_chunkw<<<768, 256, 0, stream>>>(Wh_f, whf_bf, 768);
  k_chunkw<<<768, 256, 0, stream>>>(Wh_b, whb_bf, 768);
  k_chunkw<<<768, 256, 0, stream>>>(Wh_d, whd_bf, 768);
  if (big) k_extract_bf16<<<32000, 256, 0, stream>>>(lin_w, lin_bf, 32000*256);

  k_gemm<false,false,false,false><<<dim3(6,32), 256, 0, stream>>>(
      emb_enc, Wi_f, bi_f, gi_f, 4096, 768, 256, 256, 256, 768);
  k_gemm<false,false,false,false><<<dim3(6,32), 256, 0, stream>>>(
      emb_enc, Wi_b, bi_b, gi_b, 4096, 768, 256, 256, 256, 768);
  k_gemm<false,false,false,false><<<dim3(6,16), 256, 0, stream>>>(
      emb_dec, Wi_d + 512, bi_d, gi_dx, 2048, 768, 256, 256, 768, 768);

  k_encoder<<<64, 1024, 141312, stream>>>(whf_bf, whb_bf, bh_f, bh_b, gi_f, gi_b, enc);
  k_encb2<<<Bb*TEe, 64, 0, stream>>>(enc, W2_b, encb2);

  k_gemm<false,false,true,true><<<dim3(2,32), 256, 0, stream>>>(
      enc, W2_w, nullptr, encw2, 4096, 256, 512, 512, 256, 256);
  k_gemm<false,false,false,false><<<dim3(6,32), 256, 0, stream>>>(
      enc, Wi_d, nullptr, projf, 4096, 768, 512, 512, 768, 768);
  k_projchunk<<<(Bb*16*768*8)/256, 256, 0, stream>>>(projf, projt);
  k_hinit<<<Bb, 256, 0, stream>>>(enc, sizes, W1_w, W1_b, h0);

  k_decoder<<<Bb, 1024, 144896, stream>>>(whd_bf, bh_d, gi_dx, encw2, encb2, projt, h0, outs_bf);

  if (big)
    k_gemm<true,true,false,false><<<dim3(250,16), 256, 0, stream>>>(
        outs_bf, lin_bf, lin_b, d_out, 2048, 32000, 256, 256, 256, 32000);
  else
    k_gemm<true,false,false,false><<<dim3(250,16), 256, 0, stream>>>(
        outs_bf, lin_w, lin_b, d_out, 2048, 32000, 256, 256, 256, 32000);
}